// Round 1
// baseline (206.668 us; speedup 1.0000x reference)
//
#include <hip/hip_runtime.h>

// TempCtxAttention: out[n,m,:] = (softmax over kl of q[n,h,:]·k[m,h,kl,:]/sqrt(32)) @ v, then @ Wo^T + bo
// N=256, M=256, KLEN=128, D_MODEL=256, H=8, DK=32. All f32 in/out; internal compute f16 MFMA.
// Workspace layout (u16 elements): qp[256*256] | kp[256*8*128*32] | vt[256*8*32*128] | wo[256*256]
// total 33,816,576 bytes — requires ws_size >= 34 MB.

typedef unsigned short u16;
typedef __attribute__((ext_vector_type(8))) _Float16 half8;
typedef __attribute__((ext_vector_type(4))) float f32x4;
typedef __attribute__((ext_vector_type(4))) unsigned short us4;

__device__ __forceinline__ u16 f2h(float v) {
  _Float16 h = (_Float16)v;            // v_cvt_f16_f32 (RNE)
  return __builtin_bit_cast(u16, h);
}

__device__ __forceinline__ f32x4 mf16(half8 a, half8 b, f32x4 c) {
  return __builtin_amdgcn_mfma_f32_16x16x32_f16(a, b, c, 0, 0, 0);
}

// ---------------- Wo f32 -> f16 ----------------
__global__ __launch_bounds__(256) void wo_cvt_kernel(const float* __restrict__ Wo,
                                                     u16* __restrict__ wo) {
  int i = (blockIdx.x * 256 + threadIdx.x) * 4;
  float4 g = *(const float4*)(Wo + i);
  us4 h = { f2h(g.x), f2h(g.y), f2h(g.z), f2h(g.w) };
  *(us4*)(wo + i) = h;
}

// ---------------- projections ----------------
// out = X @ W^T + bias, stored f16.
// MODE 0 (q): out[r*256 + j]
// MODE 1 (k): r=m*128+kl, j=h*32+d -> out[((m*8+h)*128+kl)*32+d]
// MODE 2 (v): transposed compute (D = W·X^T) -> out[((m*8+h)*32+d)*128+kl]
// Block: 256 thr, 64 rows x 64 cols tile. Grid = (R/64)*4, XCD-chunk remapped so the
// 4 col-tiles sharing an X row-block run consecutively on one XCD (L2 reuse of X).
template<int MODE>
__global__ __launch_bounds__(256) void proj_kernel(const float* __restrict__ X,
                                                   const float* __restrict__ W,
                                                   const float* __restrict__ bias,
                                                   u16* __restrict__ out) {
  __shared__ __align__(16) u16 xa[64 * 256];
  __shared__ __align__(16) u16 wa[64 * 256];
  int bid = blockIdx.x;
  int chunk = gridDim.x >> 3;
  int logical = (bid & 7) * chunk + (bid >> 3);   // bijective (grid % 8 == 0)
  int rb = logical >> 2, cb = logical & 3;
  int tid = threadIdx.x;

  char* xb = (char*)xa;
  char* wb_ = (char*)wa;
#pragma unroll
  for (int i = 0; i < 16; ++i) {
    int idx = tid + i * 256;
    int row = idx >> 6, c4 = idx & 63;
    int so = (row * 512 + c4 * 8) ^ ((row & 7) << 4);   // XOR swizzle (G4)
    float4 gx = *(const float4*)(X + (rb * 64 + row) * 256 + c4 * 4);
    us4 hx = { f2h(gx.x), f2h(gx.y), f2h(gx.z), f2h(gx.w) };
    *(us4*)(xb + so) = hx;
    float4 gw = *(const float4*)(W + (cb * 64 + row) * 256 + c4 * 4);
    us4 hw = { f2h(gw.x), f2h(gw.y), f2h(gw.z), f2h(gw.w) };
    *(us4*)(wb_ + so) = hw;
  }
  __syncthreads();

  int lane = tid & 63, w = tid >> 6;
  int lr = lane & 15, lq = lane >> 4;
  // MODE 2 swaps operands: A from W (rows=j), B from X (cols=r) -> D[j][r]
  const char* ab = (MODE == 2) ? wb_ : xb;
  const char* bb = (MODE == 2) ? xb : wb_;

  half8 a[8];
#pragma unroll
  for (int kk = 0; kk < 8; ++kk)
    a[kk] = *(const half8*)(ab + (((w * 16 + lr) * 512 + kk * 64 + lq * 16) ^ ((lr & 7) << 4)));

#pragma unroll
  for (int ct = 0; ct < 4; ++ct) {
    f32x4 acc = {0.f, 0.f, 0.f, 0.f};
#pragma unroll
    for (int kk = 0; kk < 8; ++kk) {
      half8 b = *(const half8*)(bb + (((ct * 16 + lr) * 512 + kk * 64 + lq * 16) ^ ((lr & 7) << 4)));
      acc = mf16(a[kk], b, acc);
    }
    if (MODE != 2) {
      int j = cb * 64 + ct * 16 + lr;
      float bj = bias[j];
#pragma unroll
      for (int rr = 0; rr < 4; ++rr) {
        int gr = rb * 64 + w * 16 + lq * 4 + rr;
        float v = acc[rr] + bj;
        if (MODE == 0) {
          out[gr * 256 + j] = f2h(v);
        } else {
          int mm = gr >> 7, kl = gr & 127, hh = j >> 5, d = j & 31;
          out[((mm * 8 + hh) * 128 + kl) * 32 + d] = f2h(v);
        }
      }
    } else {
#pragma unroll
      for (int rr = 0; rr < 4; ++rr) {
        int j = cb * 64 + w * 16 + lq * 4 + rr;   // D row = W row = output channel
        float v = acc[rr] + bias[j];
        int gr = rb * 64 + ct * 16 + lr;          // D col = X row = (m,kl)
        int mm = gr >> 7, kl = gr & 127, hh = j >> 5, d = j & 31;
        out[((mm * 8 + hh) * 32 + d) * 128 + kl] = f2h(v);
      }
    }
  }
}

// ---------------- fused attention + output projection ----------------
// grid 1024 = 256 m x 4 n-tiles (XCD-swizzled: 4 blocks of one m share an XCD L2).
// 4 waves/block, each wave owns 16 q-rows; waves fully independent (no barriers).
__global__ __launch_bounds__(256) void attn_kernel(const u16* __restrict__ qp,
                                                   const u16* __restrict__ kp,
                                                   const u16* __restrict__ vt,
                                                   const u16* __restrict__ wo,
                                                   const float* __restrict__ bo,
                                                   float* __restrict__ out) {
  __shared__ __align__(16) u16 p_lds[4 * 2048];   // per-wave [16][128] f16 P tile
  __shared__ __align__(16) u16 c_lds[4 * 4096];   // per-wave [16][256] f16 ctx tile
  int bid = blockIdx.x;
  int xcd = bid & 7, idx = bid >> 3;
  int m = xcd * 32 + (idx >> 2);
  int nt = idx & 3;
  int tid = threadIdx.x;
  int w = tid >> 6, lane = tid & 63;
  int lr = lane & 15, lq = lane >> 4;
  int n0 = nt * 64 + w * 16;
  char* Pb = (char*)p_lds + w * 4096;
  char* Cb = (char*)c_lds + w * 8192;
  const float SCL2E = (float)(1.4426950408889634 / 5.656854249492381); // log2(e)/sqrt(32)

  // Q fragments for all 8 heads, kept in registers (A-frag: row=lane&15, k=(lane>>4)*8+i)
  half8 qa[8];
#pragma unroll
  for (int h = 0; h < 8; ++h)
    qa[h] = *(const half8*)(qp + (n0 + lr) * 256 + h * 32 + lq * 8);

#pragma unroll
  for (int h = 0; h < 8; ++h) {
    // ---- scores: S[16n x 128kl], 8 MFMAs (K=32) ----
    const u16* kh = kp + (m * 8 + h) * 128 * 32;
    f32x4 s[8];
#pragma unroll
    for (int kt = 0; kt < 8; ++kt) {
      half8 kb = *(const half8*)(kh + (kt * 16 + lr) * 32 + lq * 8);
      f32x4 z = {0.f, 0.f, 0.f, 0.f};
      s[kt] = mf16(qa[h], kb, z);
    }
    // ---- wave-parallel softmax; D-layout row = lq*4+rr, col = kt*16+lr ----
    float inv[4];
#pragma unroll
    for (int rr = 0; rr < 4; ++rr) {
      int row = lq * 4 + rr;
      float mx = s[0][rr];
#pragma unroll
      for (int kt = 1; kt < 8; ++kt) mx = fmaxf(mx, s[kt][rr]);
      mx = fmaxf(mx, __shfl_xor(mx, 1));
      mx = fmaxf(mx, __shfl_xor(mx, 2));
      mx = fmaxf(mx, __shfl_xor(mx, 4));
      mx = fmaxf(mx, __shfl_xor(mx, 8));
      float sum = 0.f;
#pragma unroll
      for (int kt = 0; kt < 8; ++kt) {
        float p = __builtin_amdgcn_exp2f((s[kt][rr] - mx) * SCL2E);
        sum += p;
        // unnormalized P -> LDS [row][kl] f16, XOR-swizzled
        *(u16*)(Pb + ((row * 256 + (kt * 16 + lr) * 2) ^ ((row & 7) << 4))) = f2h(p);
      }
      sum += __shfl_xor(sum, 1);
      sum += __shfl_xor(sum, 2);
      sum += __shfl_xor(sum, 4);
      sum += __shfl_xor(sum, 8);
      inv[rr] = 1.0f / sum;   // normalization deferred to ctx
    }
    // ---- PV: ctx[16n x 32d] = P @ V, A-frags from swizzled LDS ----
    half8 pa[4];
#pragma unroll
    for (int kv = 0; kv < 4; ++kv)
      pa[kv] = *(const half8*)(Pb + ((lr * 256 + kv * 64 + lq * 16) ^ ((lr & 7) << 4)));
    const u16* vh = vt + (m * 8 + h) * 32 * 128;
#pragma unroll
    for (int jt = 0; jt < 2; ++jt) {
      f32x4 acc = {0.f, 0.f, 0.f, 0.f};
#pragma unroll
      for (int kv = 0; kv < 4; ++kv) {
        half8 vb = *(const half8*)(vh + (jt * 16 + lr) * 128 + kv * 32 + lq * 8);
        acc = mf16(pa[kv], vb, acc);
      }
      int dm = h * 32 + jt * 16 + lr;
#pragma unroll
      for (int rr = 0; rr < 4; ++rr) {
        int n = lq * 4 + rr;
        *(u16*)(Cb + ((n * 512 + dm * 2) ^ ((n & 7) << 4))) = f2h(acc[rr] * inv[rr]);
      }
    }
  }

  // ---- output projection: out[16n x 256j] = ctx @ Wo^T + bo ----
  half8 ca[8];
#pragma unroll
  for (int kk = 0; kk < 8; ++kk)
    ca[kk] = *(const half8*)(Cb + ((lr * 512 + kk * 64 + lq * 16) ^ ((lr & 7) << 4)));
#pragma unroll
  for (int jt = 0; jt < 16; ++jt) {
    f32x4 acc = {0.f, 0.f, 0.f, 0.f};
#pragma unroll
    for (int kk = 0; kk < 8; ++kk) {
      half8 wb = *(const half8*)(wo + (jt * 16 + lr) * 256 + kk * 32 + lq * 8);
      acc = mf16(ca[kk], wb, acc);
    }
    int col = jt * 16 + lr;
    float bj = bo[col];
#pragma unroll
    for (int rr = 0; rr < 4; ++rr) {
      int n = n0 + lq * 4 + rr;
      out[(n * 256 + m) * 256 + col] = acc[rr] + bj;
    }
  }
}

extern "C" void kernel_launch(void* const* d_in, const int* in_sizes, int n_in,
                              void* d_out, int out_size, void* d_ws, size_t ws_size,
                              hipStream_t stream) {
  (void)in_sizes; (void)n_in; (void)out_size; (void)ws_size;
  const float* query = (const float*)d_in[0];
  const float* key   = (const float*)d_in[1];
  const float* value = (const float*)d_in[2];
  const float* Wq = (const float*)d_in[3];
  const float* bq = (const float*)d_in[4];
  const float* Wk = (const float*)d_in[5];
  const float* bk = (const float*)d_in[6];
  const float* Wv = (const float*)d_in[7];
  const float* bv = (const float*)d_in[8];
  const float* Wo = (const float*)d_in[9];
  const float* bo = (const float*)d_in[10];
  float* out = (float*)d_out;

  u16* ws = (u16*)d_ws;
  u16* qp = ws;                 // [256][256]
  u16* kp = qp + 65536;         // [256][8][128][32]
  u16* vt = kp + 8388608;       // [256][8][32][128]
  u16* wo = vt + 8388608;       // [256][256]

  wo_cvt_kernel<<<64, 256, 0, stream>>>(Wo, wo);
  proj_kernel<0><<<16,   256, 0, stream>>>(query, Wq, bq, qp);
  proj_kernel<1><<<2048, 256, 0, stream>>>(key,   Wk, bk, kp);
  proj_kernel<2><<<2048, 256, 0, stream>>>(value, Wv, bv, vt);
  attn_kernel<<<1024, 256, 0, stream>>>(qp, kp, vt, wo, bo, out);
}

// Round 2
// 132.891 us; speedup vs baseline: 1.5552x; 1.5552x over previous
//
#include <hip/hip_runtime.h>

// TempCtxAttention — f16 MFMA pipeline.
// ws (u16 elements): kp[256*8*128*32] | vt[256*8*32*128] | qp[256*256] | wo16[256*256] | ctx[65536*256]
// total 33,685,504 u16 = 64.25 MB.

typedef unsigned short u16;
typedef unsigned int u32;
typedef __attribute__((ext_vector_type(8))) _Float16 half8;
typedef __attribute__((ext_vector_type(4))) float f32x4;
typedef __attribute__((ext_vector_type(4))) unsigned short us4;
typedef __attribute__((ext_vector_type(2))) unsigned int u32x2;

__device__ __forceinline__ u16 f2h(float v) {
  _Float16 h = (_Float16)v;            // v_cvt_f16_f32 (RNE)
  return __builtin_bit_cast(u16, h);
}
__device__ __forceinline__ u32 pk2(float lo, float hi) {   // 2xf16 packed (RNE)
  return (u32)f2h(lo) | ((u32)f2h(hi) << 16);
}
__device__ __forceinline__ f32x4 mf16(half8 a, half8 b, f32x4 c) {
  return __builtin_amdgcn_mfma_f32_16x16x32_f16(a, b, c, 0, 0, 0);
}

// ---------------- Wo f32 -> f16 ----------------
__global__ __launch_bounds__(256) void wo_cvt_kernel(const float* __restrict__ Wo,
                                                     u16* __restrict__ wo) {
  int i = (blockIdx.x * 256 + threadIdx.x) * 4;
  float4 g = *(const float4*)(Wo + i);
  us4 h = { f2h(g.x), f2h(g.y), f2h(g.z), f2h(g.w) };
  *(us4*)(wo + i) = h;
}

// ---------------- projections (unchanged from R1, passed) ----------------
template<int MODE>
__global__ __launch_bounds__(256) void proj_kernel(const float* __restrict__ X,
                                                   const float* __restrict__ W,
                                                   const float* __restrict__ bias,
                                                   u16* __restrict__ out) {
  __shared__ __align__(16) u16 xa[64 * 256];
  __shared__ __align__(16) u16 wa[64 * 256];
  int bid = blockIdx.x;
  int chunk = gridDim.x >> 3;
  int logical = (bid & 7) * chunk + (bid >> 3);
  int rb = logical >> 2, cb = logical & 3;
  int tid = threadIdx.x;

  char* xb = (char*)xa;
  char* wb_ = (char*)wa;
#pragma unroll
  for (int i = 0; i < 16; ++i) {
    int idx = tid + i * 256;
    int row = idx >> 6, c4 = idx & 63;
    int so = (row * 512 + c4 * 8) ^ ((row & 7) << 4);
    float4 gx = *(const float4*)(X + (rb * 64 + row) * 256 + c4 * 4);
    us4 hx = { f2h(gx.x), f2h(gx.y), f2h(gx.z), f2h(gx.w) };
    *(us4*)(xb + so) = hx;
    float4 gw = *(const float4*)(W + (cb * 64 + row) * 256 + c4 * 4);
    us4 hw = { f2h(gw.x), f2h(gw.y), f2h(gw.z), f2h(gw.w) };
    *(us4*)(wb_ + so) = hw;
  }
  __syncthreads();

  int lane = tid & 63, w = tid >> 6;
  int lr = lane & 15, lq = lane >> 4;
  const char* ab = (MODE == 2) ? wb_ : xb;
  const char* bb = (MODE == 2) ? xb : wb_;

  half8 a[8];
#pragma unroll
  for (int kk = 0; kk < 8; ++kk)
    a[kk] = *(const half8*)(ab + (((w * 16 + lr) * 512 + kk * 64 + lq * 16) ^ ((lr & 7) << 4)));

#pragma unroll
  for (int ct = 0; ct < 4; ++ct) {
    f32x4 acc = {0.f, 0.f, 0.f, 0.f};
#pragma unroll
    for (int kk = 0; kk < 8; ++kk) {
      half8 b = *(const half8*)(bb + (((ct * 16 + lr) * 512 + kk * 64 + lq * 16) ^ ((lr & 7) << 4)));
      acc = mf16(a[kk], b, acc);
    }
    if (MODE != 2) {
      int j = cb * 64 + ct * 16 + lr;
      float bj = bias[j];
#pragma unroll
      for (int rr = 0; rr < 4; ++rr) {
        int gr = rb * 64 + w * 16 + lq * 4 + rr;
        float v = acc[rr] + bj;
        if (MODE == 0) {
          out[gr * 256 + j] = f2h(v);
        } else {
          int mm = gr >> 7, kl = gr & 127, hh = j >> 5, d = j & 31;
          out[((mm * 8 + hh) * 128 + kl) * 32 + d] = f2h(v);
        }
      }
    } else {
#pragma unroll
      for (int rr = 0; rr < 4; ++rr) {
        int j = cb * 64 + w * 16 + lq * 4 + rr;
        float v = acc[rr] + bias[j];
        int gr = rb * 64 + ct * 16 + lr;
        int mm = gr >> 7, kl = gr & 127, hh = j >> 5, d = j & 31;
        out[((mm * 8 + hh) * 32 + d) * 128 + kl] = f2h(v);
      }
    }
  }
}

// ---------------- attention -> ctx (f16) ----------------
// grid 1024 = 256 m x 4 n-tiles (XCD-swizzled). 4 waves/block, fully independent.
// Swapped operands: S^T = mfma(K, Q)  [lane holds S^T[kl=kt*16+lq*4+rr][n=lr]]
//                   ctx^T = mfma(V^T, P^T)  [lane holds ctx^T[d=jt*16+lq*4+rr][n=lr]]
__global__ __launch_bounds__(256, 4) void attn_ctx_kernel(const u16* __restrict__ qp,
                                                          const u16* __restrict__ kp,
                                                          const u16* __restrict__ vt,
                                                          u16* __restrict__ ctx) {
  __shared__ __align__(16) u16 p_lds[4 * 2048];   // per-wave [16 n][128 kl] f16, XOR-swizzled
  int bid = blockIdx.x;
  int xcd = bid & 7, idx = bid >> 3;
  int m = xcd * 32 + (idx >> 2);
  int nt = idx & 3;
  int tid = threadIdx.x;
  int w = tid >> 6, lane = tid & 63;
  int lr = lane & 15, lq = lane >> 4;
  int n = nt * 64 + w * 16 + lr;                  // this lane's n (MFMA col)
  char* Pb = (char*)p_lds + w * 4096;
  int swz = (lr & 7) << 4;
  const float SCL2E = 0.25506980508f;             // log2(e)/sqrt(32)

  half8 qa[8];                                    // B-frag: col=n, k=d=lq*8+i
#pragma unroll
  for (int h = 0; h < 8; ++h)
    qa[h] = *(const half8*)(qp + n * 256 + h * 32 + lq * 8);

#pragma unroll
  for (int h = 0; h < 8; ++h) {
    const u16* kh = kp + (m * 8 + h) * 4096;      // [128 kl][32 d]
    const u16* vh = vt + (m * 8 + h) * 4096;      // [32 d][128 kl]
    // ---- scores^T: 8 MFMAs, A = K rows (kl), B = Q cols (n) ----
    f32x4 s[8];
#pragma unroll
    for (int kt = 0; kt < 8; ++kt) {
      half8 ka = *(const half8*)(kh + (kt * 16 + lr) * 32 + lq * 8);
      f32x4 z = {0.f, 0.f, 0.f, 0.f};
      s[kt] = mf16(ka, qa[h], z);
    }
    // ---- softmax over kl for column n=lr: local 32 + shfl over lq groups ----
    float mx = s[0][0];
#pragma unroll
    for (int kt = 0; kt < 8; ++kt)
#pragma unroll
      for (int rr = 0; rr < 4; ++rr) mx = fmaxf(mx, s[kt][rr]);
    mx = fmaxf(mx, __shfl_xor(mx, 16));
    mx = fmaxf(mx, __shfl_xor(mx, 32));
    float sum = 0.f;
#pragma unroll
    for (int kt = 0; kt < 8; ++kt) {
      float p0 = __builtin_amdgcn_exp2f((s[kt][0] - mx) * SCL2E);
      float p1 = __builtin_amdgcn_exp2f((s[kt][1] - mx) * SCL2E);
      float p2 = __builtin_amdgcn_exp2f((s[kt][2] - mx) * SCL2E);
      float p3 = __builtin_amdgcn_exp2f((s[kt][3] - mx) * SCL2E);
      sum += (p0 + p1) + (p2 + p3);
      u32x2 pw = { pk2(p0, p1), pk2(p2, p3) };
      *(u32x2*)(Pb + ((lr * 256 + kt * 32 + lq * 8) ^ swz)) = pw;   // P[n=lr][kl]
    }
    sum += __shfl_xor(sum, 16);
    sum += __shfl_xor(sum, 32);
    float inv = 1.0f / sum;                       // deferred normalization (per-lane n)
    // ---- P^T B-frags: col=n=lr, k=kl=kv*32+lq*8+i ----
    half8 pb[4];
#pragma unroll
    for (int kv = 0; kv < 4; ++kv)
      pb[kv] = *(const half8*)(Pb + ((lr * 256 + kv * 64 + lq * 16) ^ swz));
    // ---- ctx^T = V^T @ P^T; store packed (d-consecutive) ----
#pragma unroll
    for (int jt = 0; jt < 2; ++jt) {
      f32x4 acc = {0.f, 0.f, 0.f, 0.f};
#pragma unroll
      for (int kv = 0; kv < 4; ++kv) {
        half8 va = *(const half8*)(vh + (jt * 16 + lr) * 128 + kv * 32 + lq * 8);
        acc = mf16(va, pb[kv], acc);
      }
      us4 st = { f2h(acc[0] * inv), f2h(acc[1] * inv), f2h(acc[2] * inv), f2h(acc[3] * inv) };
      *(us4*)(ctx + (n * 256 + m) * 256 + h * 32 + jt * 16 + lq * 4) = st;
    }
  }
}

// ---------------- output projection GEMM: out[65536][256] = ctx @ wo^T + bo ----------------
// grid 512 = 256 rowtiles(BM=256) x 2 coltiles(BN=128); 8 waves (4r x 2c), wave tile 64x64.
// wo coltile staged once in 64KB XOR-swizzled LDS; A-frags streamed from global.
__global__ __launch_bounds__(512, 4) void outproj_kernel(const u16* __restrict__ ctx,
                                                         const u16* __restrict__ wo_g,
                                                         const float* __restrict__ bo,
                                                         float* __restrict__ out) {
  __shared__ __align__(16) u16 bs[128 * 256];     // [j][dm] f16, 64KB, XOR-swizzled
  int bid = blockIdx.x;
  int rt = bid >> 1, ct = bid & 1;
  int tid = threadIdx.x;
  // stage: physical 16B-block b of row j holds logical block b^(j&7)
#pragma unroll
  for (int it = 0; it < 8; ++it) {
    int idx = it * 512 + tid;
    int j = idx >> 5, b = idx & 31;
    uint4 v = *(const uint4*)((const char*)wo_g + (ct * 128 + j) * 512 + ((b ^ (j & 7)) * 16));
    *(uint4*)((char*)bs + j * 512 + b * 16) = v;
  }
  __syncthreads();

  int wv = tid >> 6, lane = tid & 63;
  int lr = lane & 15, lq = lane >> 4;
  int wr = wv >> 1, wc = wv & 1;
  int r0 = rt * 256 + wr * 64;

  f32x4 acc[4][4];
#pragma unroll
  for (int mt = 0; mt < 4; ++mt)
#pragma unroll
    for (int ntl = 0; ntl < 4; ++ntl) acc[mt][ntl] = f32x4{0.f, 0.f, 0.f, 0.f};

#pragma unroll
  for (int kk = 0; kk < 8; ++kk) {
    half8 bfr[4];
#pragma unroll
    for (int ntl = 0; ntl < 4; ++ntl) {
      int j = wc * 64 + ntl * 16 + lr;
      bfr[ntl] = *(const half8*)((char*)bs + j * 512 + ((kk * 64 + lq * 16) ^ ((j & 7) << 4)));
    }
#pragma unroll
    for (int mt = 0; mt < 4; ++mt) {
      half8 a = *(const half8*)(ctx + (r0 + mt * 16 + lr) * 256 + kk * 32 + lq * 8);
#pragma unroll
      for (int ntl = 0; ntl < 4; ++ntl)
        acc[mt][ntl] = mf16(a, bfr[ntl], acc[mt][ntl]);
    }
  }
  // epilogue
#pragma unroll
  for (int ntl = 0; ntl < 4; ++ntl) {
    int j = ct * 128 + wc * 64 + ntl * 16 + lr;
    float bj = bo[j];
#pragma unroll
    for (int mt = 0; mt < 4; ++mt)
#pragma unroll
      for (int rr = 0; rr < 4; ++rr)
        out[(r0 + mt * 16 + lq * 4 + rr) * 256 + j] = acc[mt][ntl][rr] + bj;
  }
}

extern "C" void kernel_launch(void* const* d_in, const int* in_sizes, int n_in,
                              void* d_out, int out_size, void* d_ws, size_t ws_size,
                              hipStream_t stream) {
  (void)in_sizes; (void)n_in; (void)out_size; (void)ws_size;
  const float* query = (const float*)d_in[0];
  const float* key   = (const float*)d_in[1];
  const float* value = (const float*)d_in[2];
  const float* Wq = (const float*)d_in[3];
  const float* bq = (const float*)d_in[4];
  const float* Wk = (const float*)d_in[5];
  const float* bk = (const float*)d_in[6];
  const float* Wv = (const float*)d_in[7];
  const float* bv = (const float*)d_in[8];
  const float* Wo = (const float*)d_in[9];
  const float* bo = (const float*)d_in[10];
  float* out = (float*)d_out;

  u16* ws = (u16*)d_ws;
  u16* kp   = ws;                  // [256*8][128][32]
  u16* vt   = kp + 8388608;        // [256*8][32][128]
  u16* qp   = vt + 8388608;        // [256][256]
  u16* wo16 = qp + 65536;          // [256][256]
  u16* ctx  = wo16 + 65536;        // [65536][256]

  wo_cvt_kernel<<<64, 256, 0, stream>>>(Wo, wo16);
  proj_kernel<0><<<16,   256, 0, stream>>>(query, Wq, bq, qp);
  proj_kernel<1><<<2048, 256, 0, stream>>>(key,   Wk, bk, kp);
  proj_kernel<2><<<2048, 256, 0, stream>>>(value, Wv, bv, vt);
  attn_ctx_kernel<<<1024, 256, 0, stream>>>(qp, kp, vt, ctx);
  outproj_kernel<<<512, 512, 0, stream>>>(ctx, wo16, bo, out);
}